// Round 1
// baseline (9152.854 us; speedup 1.0000x reference)
//
#include <hip/hip_runtime.h>
#include <hip/hip_bf16.h>
#include <stdint.h>

// Problem constants (T,B,I,H from the reference)
#define T_STEPS 512
#define BATCH   64
#define IN_DIM  128
#define HID     1024
#define KTOT    (HID + IN_DIM)   // 1152: concat [H | X] against [W_hh ; W_ih]
#define NH      64               // one WG per 16-wide h-slice
#define NSLICE  (HID / NH)       // 16
#define NWAVES  4
#define THREADS (NWAVES * 64)

typedef float f32x4 __attribute__((ext_vector_type(4)));
typedef short s16x8 __attribute__((ext_vector_type(8)));

__device__ __forceinline__ uint32_t cvt_pk_bf16(float a, float b) {
    uint32_t r;
    asm("v_cvt_pk_bf16_f32 %0, %1, %2" : "=v"(r) : "v"(a), "v"(b));
    return r;
}

union frag_u { uint32_t u[4]; s16x8 s; };

__device__ __forceinline__ s16x8 pack_bf16x8(f32x4 a, f32x4 b) {
    frag_u f;
    f.u[0] = cvt_pk_bf16(a.x, a.y);
    f.u[1] = cvt_pk_bf16(a.z, a.w);
    f.u[2] = cvt_pk_bf16(b.x, b.y);
    f.u[3] = cvt_pk_bf16(b.z, b.w);
    return f.s;
}

// fast tanh: 1 - 2/(e^{2x}+1); saturates correctly for |x| large
__device__ __forceinline__ float tanh_fast(float x) {
    float e = __expf(2.0f * x);
    return 1.0f - 2.0f * __builtin_amdgcn_rcpf(e + 1.0f);
}

__global__ __launch_bounds__(THREADS, 1)
void rnn_step_kernel(const float* __restrict__ X, const float* __restrict__ Wih,
                     const float* __restrict__ Whh, const float* __restrict__ bh,
                     const float* __restrict__ H0, float* __restrict__ out,
                     int* __restrict__ flags)
{
    // W slice resident in LDS for the whole kernel, bf16, XOR-swizzled.
    // Layout: col-major [c][k] so a B-fragment (8 consecutive k, fixed col)
    // is one ds_read_b128. Swizzle byte ^= (c&7)<<4 breaks the 2304B-stride
    // 16-way bank conflict down to <=2-way (free).
    __shared__ uint16_t Wlds[NSLICE * KTOT];

    const int tid = threadIdx.x;
    const int wg  = blockIdx.x;       // h-block index
    const int h0  = wg * NSLICE;

    // ---- stage W_hh[:,h0:h0+16] and W_ih[:,h0:h0+16] into LDS as bf16 ----
    for (int e = tid; e < NSLICE * KTOT; e += THREADS) {
        int c = e & (NSLICE - 1);
        int k = e >> 4;               // log2(NSLICE)
        float w = (k < HID) ? Whh[(size_t)k * HID + h0 + c]
                            : Wih[(size_t)(k - HID) * HID + h0 + c];
        uint32_t u = __builtin_bit_cast(uint32_t, w);
        uint32_t r = (u + 0x7FFFu + ((u >> 16) & 1u)) >> 16;   // RNE to bf16
        uint32_t off = ((uint32_t)(c * KTOT + k) * 2u) ^ ((uint32_t)(c & 7) << 4);
        *(uint16_t*)((char*)Wlds + off) = (uint16_t)r;
    }
    __syncthreads();

    const int lane = tid & 63;
    const int wv   = tid >> 6;
    const int arow = lane & 15;       // A-fragment row (batch within wave tile)
    const int kg   = lane >> 4;       // 0..3 k-group
    const int b_ld = wv * 16 + arow;  // batch index for A loads
    const int c    = lane & 15;       // B col within slice == C/D col
    const int h    = h0 + c;
    const float bias = bh[h];

    const char* wbase = (const char*)Wlds;

    for (int t = 0; t < T_STEPS; ++t) {
        f32x4 acc0 = {0.f, 0.f, 0.f, 0.f};
        f32x4 acc1 = {0.f, 0.f, 0.f, 0.f};

        // ---- Phase A: input-projection part (no cross-step dependency) ----
        const float* xrow = X + ((size_t)t * BATCH + b_ld) * IN_DIM;
        #pragma unroll
        for (int kk = 0; kk < IN_DIM / 32; ++kk) {
            int kidx = kk * 32 + kg * 8;
            f32x4 f0 = *(const f32x4*)(xrow + kidx);
            f32x4 f1 = *(const f32x4*)(xrow + kidx + 4);
            s16x8 afrag = pack_bf16x8(f0, f1);
            uint32_t off = ((uint32_t)(c * KTOT + (HID + kidx)) * 2u) ^ ((uint32_t)(c & 7) << 4);
            s16x8 wfrag = *(const s16x8*)(wbase + off);
            if (kk & 1) acc1 = __builtin_amdgcn_mfma_f32_16x16x32_bf16(afrag, wfrag, acc1, 0, 0, 0);
            else        acc0 = __builtin_amdgcn_mfma_f32_16x16x32_bf16(afrag, wfrag, acc0, 0, 0, 0);
        }

        // ---- Phase B: wait until all 64 WGs published H[t-1] ----
        if (t > 0) {
            if (tid == 0) {
                while (__hip_atomic_load(&flags[t - 1], __ATOMIC_RELAXED,
                                         __HIP_MEMORY_SCOPE_AGENT) < NH) {
                    __builtin_amdgcn_s_sleep(2);
                }
                __builtin_amdgcn_fence(__ATOMIC_ACQUIRE, "agent");
            }
            __syncthreads();
        }

        const float* hsrc = (t == 0) ? (H0 + (size_t)b_ld * HID)
                                     : (out + ((size_t)(t - 1) * BATCH + b_ld) * HID);

        // ---- Phase C: recurrent part, K = 1024 ----
        #pragma unroll 8
        for (int kk = 0; kk < HID / 32; ++kk) {
            int kidx = kk * 32 + kg * 8;
            f32x4 f0 = *(const f32x4*)(hsrc + kidx);
            f32x4 f1 = *(const f32x4*)(hsrc + kidx + 4);
            s16x8 afrag = pack_bf16x8(f0, f1);
            uint32_t off = ((uint32_t)(c * KTOT + kidx) * 2u) ^ ((uint32_t)(c & 7) << 4);
            s16x8 wfrag = *(const s16x8*)(wbase + off);
            if (kk & 1) acc1 = __builtin_amdgcn_mfma_f32_16x16x32_bf16(afrag, wfrag, acc1, 0, 0, 0);
            else        acc0 = __builtin_amdgcn_mfma_f32_16x16x32_bf16(afrag, wfrag, acc0, 0, 0, 0);
        }

        // ---- Epilogue: bias + tanh, publish H[t] (C/D: col=lane&15, row=kg*4+r) ----
        #pragma unroll
        for (int r = 0; r < 4; ++r) {
            float x  = acc0[r] + acc1[r] + bias;
            float th = tanh_fast(x);
            int bm = wv * 16 + kg * 4 + r;
            out[((size_t)t * BATCH + bm) * HID + h] = th;
            if (t == T_STEPS - 1)
                out[((size_t)T_STEPS * BATCH + bm) * HID + h] = th;  // H_final
        }

        __syncthreads();  // drains all waves' stores (vmcnt(0) before s_barrier)
        if (tid == 0) {
            __threadfence();  // agent-scope release: writes visible device-wide
            __hip_atomic_fetch_add(&flags[t], 1, __ATOMIC_RELEASE,
                                   __HIP_MEMORY_SCOPE_AGENT);
        }
    }
}

extern "C" void kernel_launch(void* const* d_in, const int* in_sizes, int n_in,
                              void* d_out, int out_size, void* d_ws, size_t ws_size,
                              hipStream_t stream) {
    (void)in_sizes; (void)n_in; (void)out_size; (void)ws_size;
    const float* X   = (const float*)d_in[0];
    const float* Wih = (const float*)d_in[1];
    const float* Whh = (const float*)d_in[2];
    const float* bh  = (const float*)d_in[3];
    const float* H0  = (const float*)d_in[4];
    float* out = (float*)d_out;
    int* flags = (int*)d_ws;

    // zero the per-step arrival counters (captured as part of the graph)
    hipMemsetAsync(d_ws, 0, T_STEPS * sizeof(int), stream);
    hipLaunchKernelGGL(rnn_step_kernel, dim3(NH), dim3(THREADS), 0, stream,
                       X, Wih, Whh, bh, H0, out, flags);
}

// Round 2
// 2964.703 us; speedup vs baseline: 3.0873x; 3.0873x over previous
//
#include <hip/hip_runtime.h>
#include <hip/hip_bf16.h>
#include <stdint.h>

// Problem constants
#define T_STEPS 512
#define BATCH   64
#define IN_DIM  128
#define HID     1024
#define KTOT    (HID + IN_DIM)     // 1152: [H | X] vs [W_hh ; W_ih]
#define NH      64                 // one WG per 16-wide h-slice
#define NSLICE  16
#define NWAVES  4
#define THREADS (NWAVES * 64)
#define COMM_ELEMS (BATCH * HID)   // 65536 bf16 per parity buffer

typedef float f32x4 __attribute__((ext_vector_type(4)));
typedef short s16x8 __attribute__((ext_vector_type(8)));

__device__ __forceinline__ uint32_t cvt_pk_bf16(float a, float b) {
    uint32_t r;
    asm("v_cvt_pk_bf16_f32 %0, %1, %2" : "=v"(r) : "v"(a), "v"(b));
    return r;
}

union frag_u { uint32_t u[4]; s16x8 s; };

__device__ __forceinline__ s16x8 pack_bf16x8(f32x4 a, f32x4 b) {
    frag_u f;
    f.u[0] = cvt_pk_bf16(a.x, a.y);
    f.u[1] = cvt_pk_bf16(a.z, a.w);
    f.u[2] = cvt_pk_bf16(b.x, b.y);
    f.u[3] = cvt_pk_bf16(b.z, b.w);
    return f.s;
}

__device__ __forceinline__ uint16_t f32_to_bf16(float v) {
    uint32_t u = __builtin_bit_cast(uint32_t, v);
    return (uint16_t)((u + 0x7FFFu + ((u >> 16) & 1u)) >> 16);
}

// fast tanh: 1 - 2/(e^{2x}+1); saturates correctly for |x| large
__device__ __forceinline__ float tanh_fast(float x) {
    float e = __expf(2.0f * x);
    return 1.0f - 2.0f * __builtin_amdgcn_rcpf(e + 1.0f);
}

// 16 pipelined coherent (L1+L2-bypassing) 16B loads from one base pointer.
// TAIL = "" (leave in flight) or a trailing s_waitcnt.
#define GLD16(D, P, TAIL)                                               \
    asm volatile(                                                       \
        "global_load_dwordx4 %0, %16, off sc0 sc1\n\t"                  \
        "global_load_dwordx4 %1, %16, off offset:64 sc0 sc1\n\t"        \
        "global_load_dwordx4 %2, %16, off offset:128 sc0 sc1\n\t"       \
        "global_load_dwordx4 %3, %16, off offset:192 sc0 sc1\n\t"       \
        "global_load_dwordx4 %4, %16, off offset:256 sc0 sc1\n\t"       \
        "global_load_dwordx4 %5, %16, off offset:320 sc0 sc1\n\t"       \
        "global_load_dwordx4 %6, %16, off offset:384 sc0 sc1\n\t"       \
        "global_load_dwordx4 %7, %16, off offset:448 sc0 sc1\n\t"       \
        "global_load_dwordx4 %8, %16, off offset:512 sc0 sc1\n\t"       \
        "global_load_dwordx4 %9, %16, off offset:576 sc0 sc1\n\t"       \
        "global_load_dwordx4 %10, %16, off offset:640 sc0 sc1\n\t"      \
        "global_load_dwordx4 %11, %16, off offset:704 sc0 sc1\n\t"      \
        "global_load_dwordx4 %12, %16, off offset:768 sc0 sc1\n\t"      \
        "global_load_dwordx4 %13, %16, off offset:832 sc0 sc1\n\t"      \
        "global_load_dwordx4 %14, %16, off offset:896 sc0 sc1\n\t"      \
        "global_load_dwordx4 %15, %16, off offset:960 sc0 sc1" TAIL     \
        : "=&v"(D[0]), "=&v"(D[1]), "=&v"(D[2]), "=&v"(D[3]),           \
          "=&v"(D[4]), "=&v"(D[5]), "=&v"(D[6]), "=&v"(D[7]),           \
          "=&v"(D[8]), "=&v"(D[9]), "=&v"(D[10]), "=&v"(D[11]),         \
          "=&v"(D[12]), "=&v"(D[13]), "=&v"(D[14]), "=&v"(D[15])        \
        : "v"(P)                                                        \
        : "memory")

__global__ void rnn_init_kernel(const float* __restrict__ H0,
                                uint16_t* __restrict__ comm) {
    // fill comm parity-1 buffer (read by t=0) with bf16(H0)
    int i = blockIdx.x * 256 + threadIdx.x;
    for (int e = i; e < COMM_ELEMS; e += 64 * 256)
        comm[COMM_ELEMS + e] = f32_to_bf16(H0[e]);
}

__global__ __launch_bounds__(THREADS, 1)
void rnn_seq_kernel(const float* __restrict__ X, const float* __restrict__ Wih,
                    const float* __restrict__ Whh, const float* __restrict__ bh,
                    float* __restrict__ out, uint16_t* __restrict__ comm,
                    int* __restrict__ flags)
{
    // W slice resident in LDS (bf16, col-major [c][k], XOR-swizzled).
    __shared__ uint16_t Wlds[NSLICE * KTOT];

    const int tid = threadIdx.x;
    const int wg  = blockIdx.x;
    const int h0  = wg * NSLICE;

    for (int e = tid; e < NSLICE * KTOT; e += THREADS) {
        int cc = e & (NSLICE - 1);
        int k  = e >> 4;
        float w = (k < HID) ? Whh[(size_t)k * HID + h0 + cc]
                            : Wih[(size_t)(k - HID) * HID + h0 + cc];
        uint32_t off = ((uint32_t)(cc * KTOT + k) * 2u) ^ ((uint32_t)(cc & 7) << 4);
        *(uint16_t*)((char*)Wlds + off) = f32_to_bf16(w);
    }
    __syncthreads();

    const int lane = tid & 63;
    const int wv   = tid >> 6;
    const int arow = lane & 15;
    const int kg   = lane >> 4;
    const int b_ld = wv * 16 + arow;      // batch row this lane loads
    const int c    = lane & 15;           // output col within slice
    const int h    = h0 + c;
    const uint32_t cswz = (uint32_t)(c & 7) << 4;
    const float bias = bh[h];
    const char* wbase = (const char*)Wlds;

    int* fl = flags + wv * 64 + wg;             // my wave's flag
    const int* fpoll = flags + wv * 64 + lane;  // the 64 flags my wave needs

    for (int t = 0; t < T_STEPS; ++t) {
        f32x4 acc0 = {0.f, 0.f, 0.f, 0.f};
        f32x4 acc1 = {0.f, 0.f, 0.f, 0.f};

        // ---- Phase A: input projection (independent of recurrence) ----
        const float* xrow = X + ((size_t)t * BATCH + b_ld) * IN_DIM;
        #pragma unroll
        for (int kk = 0; kk < IN_DIM / 32; ++kk) {
            int kidx = kk * 32 + kg * 8;
            f32x4 f0 = *(const f32x4*)(xrow + kidx);
            f32x4 f1 = *(const f32x4*)(xrow + kidx + 4);
            s16x8 afrag = pack_bf16x8(f0, f1);
            uint32_t off = ((uint32_t)((c * KTOT + (HID + kidx)) * 2)) ^ cswz;
            s16x8 wfrag = *(const s16x8*)(wbase + off);
            if (kk & 1) acc1 = __builtin_amdgcn_mfma_f32_16x16x32_bf16(afrag, wfrag, acc1, 0, 0, 0);
            else        acc0 = __builtin_amdgcn_mfma_f32_16x16x32_bf16(afrag, wfrag, acc0, 0, 0, 0);
        }
        __builtin_amdgcn_sched_barrier(0);   // pin Phase A before the poll

        // ---- Phase B: wait for the 64 producer waves of H[t-1] ----
        if (t > 0) {
            for (;;) {
                int f;
                asm volatile("global_load_dword %0, %1, off sc0 sc1\n\t"
                             "s_waitcnt vmcnt(0)"
                             : "=v"(f) : "v"(fpoll) : "memory");
                if (__all(f >= t)) break;
                __builtin_amdgcn_s_sleep(1);
            }
        }

        // ---- Phase C: recurrent GEMM, K=1024, bf16 comm via L3 ----
        const uint16_t* pr = comm + (size_t)((t + 1) & 1) * COMM_ELEMS
                             + (size_t)b_ld * HID + kg * 8;
        const uint16_t* pr2 = pr + 512;
        f32x4 LA[16], LB[16];
        GLD16(LA, pr, "");                          // 16 loads in flight
        GLD16(LB, pr2, "\n\ts_waitcnt vmcnt(16)");  // +16, wait until A done
        __builtin_amdgcn_sched_barrier(0);
        #pragma unroll
        for (int kk = 0; kk < 16; ++kk) {
            int kidx = kk * 32 + kg * 8;
            uint32_t off = ((uint32_t)((c * KTOT + kidx) * 2)) ^ cswz;
            s16x8 wfrag = *(const s16x8*)(wbase + off);
            s16x8 afrag = __builtin_bit_cast(s16x8, LA[kk]);
            if (kk & 1) acc1 = __builtin_amdgcn_mfma_f32_16x16x32_bf16(afrag, wfrag, acc1, 0, 0, 0);
            else        acc0 = __builtin_amdgcn_mfma_f32_16x16x32_bf16(afrag, wfrag, acc0, 0, 0, 0);
        }
        asm volatile("s_waitcnt vmcnt(0)" ::: "memory");
        __builtin_amdgcn_sched_barrier(0);
        #pragma unroll
        for (int kk = 0; kk < 16; ++kk) {
            int kidx = 512 + kk * 32 + kg * 8;
            uint32_t off = ((uint32_t)((c * KTOT + kidx) * 2)) ^ cswz;
            s16x8 wfrag = *(const s16x8*)(wbase + off);
            s16x8 afrag = __builtin_bit_cast(s16x8, LB[kk]);
            if (kk & 1) acc1 = __builtin_amdgcn_mfma_f32_16x16x32_bf16(afrag, wfrag, acc1, 0, 0, 0);
            else        acc0 = __builtin_amdgcn_mfma_f32_16x16x32_bf16(afrag, wfrag, acc0, 0, 0, 0);
        }

        // ---- Epilogue: bias+tanh; publish bf16 comm, then flag, then fp32 out
        float th[4];
        #pragma unroll
        for (int r = 0; r < 4; ++r)
            th[r] = tanh_fast(acc0[r] + acc1[r] + bias);

        uint16_t* pw = comm + (size_t)(t & 1) * COMM_ELEMS;
        #pragma unroll
        for (int r = 0; r < 4; ++r) {
            int bm = wv * 16 + kg * 4 + r;
            uint32_t hv = f32_to_bf16(th[r]);
            const uint16_t* pa = pw + (size_t)bm * HID + h;
            asm volatile("global_store_short %0, %1, off sc0 sc1"
                         :: "v"(pa), "v"(hv) : "memory");
        }
        asm volatile("s_waitcnt vmcnt(0)" ::: "memory");  // comm globally visible
        if (lane == 0) {
            int fv = t + 1;
            asm volatile("global_store_dword %0, %1, off sc0 sc1"
                         :: "v"(fl), "v"(fv) : "memory");
        }

        // fp32 states (normal cached stores, off the critical path)
        #pragma unroll
        for (int r = 0; r < 4; ++r) {
            int bm = wv * 16 + kg * 4 + r;
            out[((size_t)t * BATCH + bm) * HID + h] = th[r];
            if (t == T_STEPS - 1)
                out[((size_t)T_STEPS * BATCH + bm) * HID + h] = th[r];
        }
    }
}

extern "C" void kernel_launch(void* const* d_in, const int* in_sizes, int n_in,
                              void* d_out, int out_size, void* d_ws, size_t ws_size,
                              hipStream_t stream) {
    (void)in_sizes; (void)n_in; (void)out_size; (void)ws_size;
    const float* X   = (const float*)d_in[0];
    const float* Wih = (const float*)d_in[1];
    const float* Whh = (const float*)d_in[2];
    const float* bh  = (const float*)d_in[3];
    const float* H0  = (const float*)d_in[4];
    float* out = (float*)d_out;

    uint16_t* comm = (uint16_t*)d_ws;                            // 2*64*1024 bf16 = 256 KB
    int* flags = (int*)((char*)d_ws + 2 * COMM_ELEMS * 2);       // 256 ints

    hipMemsetAsync(flags, 0, 256 * sizeof(int), stream);
    hipLaunchKernelGGL(rnn_init_kernel, dim3(64), dim3(256), 0, stream, H0, comm);
    hipLaunchKernelGGL(rnn_seq_kernel, dim3(NH), dim3(THREADS), 0, stream,
                       X, Wih, Whh, bh, out, comm, flags);
}

// Round 4
// 2960.342 us; speedup vs baseline: 3.0918x; 1.0015x over previous
//
#include <hip/hip_runtime.h>
#include <hip/hip_bf16.h>
#include <stdint.h>

// Problem constants
#define T_STEPS 512
#define BATCH   64
#define IN_DIM  128
#define HID     1024
#define KTOT    (HID + IN_DIM)     // 1152: [H | X] vs [W_hh ; W_ih]
#define NH      64                 // one WG per 16-wide h-slice
#define NSLICE  16
#define NWAVES  4
#define THREADS (NWAVES * 64)
#define COMM_ELEMS (BATCH * HID)   // 65536 bf16 per parity buffer

typedef float f32x4 __attribute__((ext_vector_type(4)));
typedef short s16x8 __attribute__((ext_vector_type(8)));
typedef uint32_t u32x2 __attribute__((ext_vector_type(2)));

__device__ __forceinline__ uint32_t cvt_pk_bf16(float a, float b) {
    uint32_t r;
    asm("v_cvt_pk_bf16_f32 %0, %1, %2" : "=v"(r) : "v"(a), "v"(b));
    return r;   // low16 = bf16(a), high16 = bf16(b)
}

union frag_u { uint32_t u[4]; s16x8 s; };

__device__ __forceinline__ s16x8 pack_bf16x8(f32x4 a, f32x4 b) {
    frag_u f;
    f.u[0] = cvt_pk_bf16(a.x, a.y);
    f.u[1] = cvt_pk_bf16(a.z, a.w);
    f.u[2] = cvt_pk_bf16(b.x, b.y);
    f.u[3] = cvt_pk_bf16(b.z, b.w);
    return f.s;
}

__device__ __forceinline__ uint16_t f32_to_bf16(float v) {
    uint32_t u = __builtin_bit_cast(uint32_t, v);
    return (uint16_t)((u + 0x7FFFu + ((u >> 16) & 1u)) >> 16);
}

// fast tanh: 1 - 2/(e^{2x}+1); saturates correctly for |x| large
__device__ __forceinline__ float tanh_fast(float x) {
    float e = __expf(2.0f * x);
    return 1.0f - 2.0f * __builtin_amdgcn_rcpf(e + 1.0f);
}

// 16 pipelined coherent (L1/L2-bypassing) 16B loads from one base pointer.
#define GLD16(D, P, TAIL)                                               \
    asm volatile(                                                       \
        "global_load_dwordx4 %0, %16, off sc0 sc1\n\t"                  \
        "global_load_dwordx4 %1, %16, off offset:64 sc0 sc1\n\t"        \
        "global_load_dwordx4 %2, %16, off offset:128 sc0 sc1\n\t"       \
        "global_load_dwordx4 %3, %16, off offset:192 sc0 sc1\n\t"       \
        "global_load_dwordx4 %4, %16, off offset:256 sc0 sc1\n\t"       \
        "global_load_dwordx4 %5, %16, off offset:320 sc0 sc1\n\t"       \
        "global_load_dwordx4 %6, %16, off offset:384 sc0 sc1\n\t"       \
        "global_load_dwordx4 %7, %16, off offset:448 sc0 sc1\n\t"       \
        "global_load_dwordx4 %8, %16, off offset:512 sc0 sc1\n\t"       \
        "global_load_dwordx4 %9, %16, off offset:576 sc0 sc1\n\t"       \
        "global_load_dwordx4 %10, %16, off offset:640 sc0 sc1\n\t"      \
        "global_load_dwordx4 %11, %16, off offset:704 sc0 sc1\n\t"      \
        "global_load_dwordx4 %12, %16, off offset:768 sc0 sc1\n\t"      \
        "global_load_dwordx4 %13, %16, off offset:832 sc0 sc1\n\t"      \
        "global_load_dwordx4 %14, %16, off offset:896 sc0 sc1\n\t"      \
        "global_load_dwordx4 %15, %16, off offset:960 sc0 sc1" TAIL     \
        : "=&v"(D[0]), "=&v"(D[1]), "=&v"(D[2]), "=&v"(D[3]),           \
          "=&v"(D[4]), "=&v"(D[5]), "=&v"(D[6]), "=&v"(D[7]),           \
          "=&v"(D[8]), "=&v"(D[9]), "=&v"(D[10]), "=&v"(D[11]),         \
          "=&v"(D[12]), "=&v"(D[13]), "=&v"(D[14]), "=&v"(D[15])        \
        : "v"(P)                                                        \
        : "memory")

__global__ void rnn_init_kernel(const float* __restrict__ H0,
                                uint16_t* __restrict__ comm) {
    // fill comm parity-1 buffer (read by t=0) with bf16(H0)
    int i = blockIdx.x * 256 + threadIdx.x;
    for (int e = i; e < COMM_ELEMS; e += 64 * 256)
        comm[COMM_ELEMS + e] = f32_to_bf16(H0[e]);
}

__global__ __launch_bounds__(THREADS, 1)
void rnn_seq_kernel(const float* __restrict__ X, const float* __restrict__ Wih,
                    const float* __restrict__ Whh, const float* __restrict__ bh,
                    float* __restrict__ out, uint16_t* __restrict__ comm,
                    int* __restrict__ flags)
{
    // W slice resident in LDS in MFMA-FRAGMENT ORDER (bf16):
    //   element (k, c) with kk=k>>5, kg=(k>>3)&3, j=k&7 lives at byte
    //   kk*1024 + kg*256 + c*16 + 2j.
    // A wave's ds_read_b128 for step kk is then base(lane)=lane*16 +
    // offset:kk*1024 -- lane-linear, conflict-free by construction, and a
    // bijection of (kk,kg,c,j) so no self-overwrite (round-3 lesson).
    __shared__ uint16_t Wlds[NSLICE * KTOT];

    const int tid = threadIdx.x;
    const int wg  = blockIdx.x;
    const int h0  = wg * NSLICE;

    for (int e = tid; e < NSLICE * KTOT; e += THREADS) {
        int c = e & (NSLICE - 1);
        int k = e >> 4;
        float w = (k < HID) ? Whh[(size_t)k * HID + h0 + c]
                            : Wih[(size_t)(k - HID) * HID + h0 + c];
        uint32_t off = (uint32_t)((k >> 5) * 1024 + (((k >> 3) & 3) * 256)
                                  + c * 16 + (k & 7) * 2);
        *(uint16_t*)((char*)Wlds + off) = f32_to_bf16(w);
    }
    __syncthreads();

    const int lane = tid & 63;
    const int wv   = tid >> 6;
    const int cb   = lane & 15;         // W-col within slice AND batch-within-wave
    const int kg   = lane >> 4;         // k-group 0..3
    const int b_ld = wv * 16 + cb;      // batch row this lane loads/owns
    const char* wfb = (const char*)Wlds + lane * 16;   // per-lane fragment base

    // D = mfma(Wfrag, Hfrag): rows = h (kg*4+r), cols = batch (cb).
    // Lane owns h = h0 + kg*4 + {0..3} for batch b_ld -> contiguous stores.
    const f32x4 bv = *(const f32x4*)(bh + h0 + kg * 4);

    int* fl = flags + wv * 64 + wg;             // my wave's flag
    const int* fpoll = flags + wv * 64 + lane;  // the 64 flags my wave needs

    const uint16_t* rbase = comm + (size_t)b_ld * HID + kg * 8;          // consumer
    uint16_t* cwb = comm + (size_t)b_ld * HID + h0 + kg * 4;             // producer
    float* obase = out + (size_t)b_ld * HID + h0 + kg * 4;

    for (int t = 0; t < T_STEPS; ++t) {
        f32x4 acc0 = {0.f, 0.f, 0.f, 0.f};
        f32x4 acc1 = {0.f, 0.f, 0.f, 0.f};

        // ---- Phase A: input projection (independent of recurrence) ----
        const float* xrow = X + ((size_t)t * BATCH + b_ld) * IN_DIM;
        #pragma unroll
        for (int kk = 0; kk < IN_DIM / 32; ++kk) {
            int kidx = kk * 32 + kg * 8;
            f32x4 f0 = *(const f32x4*)(xrow + kidx);
            f32x4 f1 = *(const f32x4*)(xrow + kidx + 4);
            s16x8 xf = pack_bf16x8(f0, f1);
            s16x8 wf = *(const s16x8*)(wfb + (32 + kk) * 1024);
            if (kk & 1) acc1 = __builtin_amdgcn_mfma_f32_16x16x32_bf16(wf, xf, acc1, 0, 0, 0);
            else        acc0 = __builtin_amdgcn_mfma_f32_16x16x32_bf16(wf, xf, acc0, 0, 0, 0);
        }
        __builtin_amdgcn_sched_barrier(0);   // pin Phase A before the poll

        // ---- Phase B: wait for the 64 producer waves of H[t-1] ----
        // NOTE: the vmcnt(0) here also guarantees ZERO outstanding vmem ops
        // before Phase C, which the GLD16 vmcnt(16) count relies on.
        if (t > 0) {
            for (;;) {
                int f;
                asm volatile("global_load_dword %0, %1, off sc0 sc1\n\t"
                             "s_waitcnt vmcnt(0)"
                             : "=v"(f) : "v"(fpoll) : "memory");
                if (__all(f >= t)) break;
            }
        }

        // ---- Phase C: recurrent GEMM, K=1024, bf16 comm via L3 ----
        const uint16_t* pr = rbase + (size_t)((t + 1) & 1) * COMM_ELEMS;
        f32x4 LA[16], LB[16];
        GLD16(LA, pr, "");                               // 16 loads in flight
        GLD16(LB, pr + 512, "\n\ts_waitcnt vmcnt(16)");  // +16, wait until A done
        __builtin_amdgcn_sched_barrier(0);
        #pragma unroll
        for (int kk = 0; kk < 16; ++kk) {
            s16x8 wf = *(const s16x8*)(wfb + kk * 1024);
            s16x8 af = __builtin_bit_cast(s16x8, LA[kk]);
            if (kk & 1) acc1 = __builtin_amdgcn_mfma_f32_16x16x32_bf16(wf, af, acc1, 0, 0, 0);
            else        acc0 = __builtin_amdgcn_mfma_f32_16x16x32_bf16(wf, af, acc0, 0, 0, 0);
        }
        asm volatile("s_waitcnt vmcnt(0)" ::: "memory");
        __builtin_amdgcn_sched_barrier(0);
        #pragma unroll
        for (int kk = 0; kk < 16; ++kk) {
            s16x8 wf = *(const s16x8*)(wfb + (16 + kk) * 1024);
            s16x8 af = __builtin_bit_cast(s16x8, LB[kk]);
            if (kk & 1) acc1 = __builtin_amdgcn_mfma_f32_16x16x32_bf16(wf, af, acc1, 0, 0, 0);
            else        acc0 = __builtin_amdgcn_mfma_f32_16x16x32_bf16(wf, af, acc0, 0, 0, 0);
        }

        // ---- Epilogue: bias+tanh. Lane holds h = h0+kg*4+{0..3} of batch b_ld.
        float th0 = tanh_fast(acc0[0] + acc1[0] + bv.x);
        float th1 = tanh_fast(acc0[1] + acc1[1] + bv.y);
        float th2 = tanh_fast(acc0[2] + acc1[2] + bv.z);
        float th3 = tanh_fast(acc0[3] + acc1[3] + bv.w);

        // publish bf16 comm (one coalesced 8B store), drain, then flag
        u32x2 cd;
        cd.x = cvt_pk_bf16(th0, th1);
        cd.y = cvt_pk_bf16(th2, th3);
        uint16_t* pw = cwb + (size_t)(t & 1) * COMM_ELEMS;
        asm volatile("global_store_dwordx2 %0, %1, off sc0 sc1"
                     :: "v"(pw), "v"(cd) : "memory");
        asm volatile("s_waitcnt vmcnt(0)" ::: "memory");  // comm globally visible
        if (lane == 0) {
            int fv = t + 1;
            asm volatile("global_store_dword %0, %1, off sc0 sc1"
                         :: "v"(fl), "v"(fv) : "memory");
        }

        // fp32 states (normal cached 16B store, off the critical path)
        f32x4 vo; vo.x = th0; vo.y = th1; vo.z = th2; vo.w = th3;
        *(f32x4*)(obase + (size_t)t * BATCH * HID) = vo;
        if (t == T_STEPS - 1)
            *(f32x4*)(obase + (size_t)T_STEPS * BATCH * HID) = vo;  // H_final
    }
}

extern "C" void kernel_launch(void* const* d_in, const int* in_sizes, int n_in,
                              void* d_out, int out_size, void* d_ws, size_t ws_size,
                              hipStream_t stream) {
    (void)in_sizes; (void)n_in; (void)out_size; (void)ws_size;
    const float* X   = (const float*)d_in[0];
    const float* Wih = (const float*)d_in[1];
    const float* Whh = (const float*)d_in[2];
    const float* bh  = (const float*)d_in[3];
    const float* H0  = (const float*)d_in[4];
    float* out = (float*)d_out;

    uint16_t* comm = (uint16_t*)d_ws;                            // 2*64*1024 bf16 = 256 KB
    int* flags = (int*)((char*)d_ws + 2 * COMM_ELEMS * 2);       // 256 ints

    hipMemsetAsync(flags, 0, 256 * sizeof(int), stream);
    hipLaunchKernelGGL(rnn_init_kernel, dim3(64), dim3(256), 0, stream, H0, comm);
    hipLaunchKernelGGL(rnn_seq_kernel, dim3(NH), dim3(THREADS), 0, stream,
                       X, Wih, Whh, bh, out, comm, flags);
}